// Round 2
// baseline (199.968 us; speedup 1.0000x reference)
//
#include <hip/hip_runtime.h>

typedef __bf16 bf16x8 __attribute__((ext_vector_type(8)));
typedef float f32x4 __attribute__((ext_vector_type(4)));

#define T_SEQ 8192
#define NB 2
#define CDIM 1024
#define HDIM 64
#define NROWS (NB * T_SEQ)  // 16384

static __device__ __forceinline__ unsigned short f2b(float f) {
    union { float f; unsigned u; } a; a.f = f;
    unsigned r = a.u + 0x7FFFu + ((a.u >> 16) & 1u);   // RNE to bf16
    return (unsigned short)(r >> 16);
}

static __device__ __forceinline__ bf16x8 pack8(float4 a, float4 b) {
    union { bf16x8 v; unsigned short u[8]; } r;
    r.u[0] = f2b(a.x); r.u[1] = f2b(a.y); r.u[2] = f2b(a.z); r.u[3] = f2b(a.w);
    r.u[4] = f2b(b.x); r.u[5] = f2b(b.y); r.u[6] = f2b(b.z); r.u[7] = f2b(b.w);
    return r.v;
}

// ---------------------------------------------------------------------------
// Kernel 1: WT[m][n][k] = W_m[k][n] as bf16 bits.  m in {q,k,v}, n<64, k<1024.
// ---------------------------------------------------------------------------
__global__ __launch_bounds__(256) void wt_kernel(const float* __restrict__ Wq,
                                                 const float* __restrict__ Wk,
                                                 const float* __restrict__ Wv,
                                                 unsigned short* __restrict__ WT) {
    int idx = blockIdx.x * 256 + threadIdx.x;  // < 3*64*1024 = 196608
    int m   = idx >> 16;
    int rem = idx & 65535;
    int n = rem >> 10, k = rem & 1023;
    const float* W = (m == 0) ? Wq : (m == 1) ? Wk : Wv;
    WT[idx] = f2b(W[k * HDIM + n]);
}

// ---------------------------------------------------------------------------
// Kernel 2: fused QKV projection, LDS-free.
// Wave owns 16 rows x 192 cols. A-frags straight from global x (f32->bf16 in
// reg, double-buffered); B-frags straight from L2-resident WT. No barriers.
// ---------------------------------------------------------------------------
__global__ __launch_bounds__(256) void qkv_kernel(const float* __restrict__ x,
                                                  const unsigned short* __restrict__ WT,
                                                  float* __restrict__ q,
                                                  float* __restrict__ k,
                                                  float* __restrict__ v) {
    int tid  = threadIdx.x;
    int lane = tid & 63;
    int w    = tid >> 6;
    int lr   = lane & 15, lg = lane >> 4;
    long r0  = ((long)blockIdx.x * 4 + w) * 16;

    const float* xrow = x + (r0 + lr) * CDIM + lg * 8;
    const unsigned short* bbase = WT + (long)lr * CDIM + lg * 8;

    f32x4 acc[12];
    #pragma unroll
    for (int ni = 0; ni < 12; ++ni) acc[ni] = (f32x4){0.f, 0.f, 0.f, 0.f};

    float4 c0 = *(const float4*)(xrow + 0);
    float4 c1 = *(const float4*)(xrow + 4);

    for (int ks = 0; ks < CDIM; ks += 32) {
        int kn = (ks + 32) & (CDIM - 1);          // wraps to 0 on last iter (cached)
        float4 n0 = *(const float4*)(xrow + kn + 0);
        float4 n1 = *(const float4*)(xrow + kn + 4);
        bf16x8 af = pack8(c0, c1);
        #pragma unroll
        for (int ni = 0; ni < 12; ++ni) {
            bf16x8 bf = *(const bf16x8*)(bbase + ni * 16 * CDIM + ks);
            acc[ni] = __builtin_amdgcn_mfma_f32_16x16x32_bf16(af, bf, acc[ni], 0, 0, 0);
        }
        c0 = n0; c1 = n1;
    }

    // C/D layout: col = lane&15, row = (lane>>4)*4 + j (measured)
    #pragma unroll
    for (int ni = 0; ni < 12; ++ni) {
        int cg  = ni * 16 + lr;            // 0..191
        int mat = cg >> 6, cc = cg & 63;
        float* op = (mat == 0) ? q : (mat == 1) ? k : v;
        long rbase = r0 + lg * 4;
        #pragma unroll
        for (int j = 0; j < 4; ++j)
            op[(rbase + j) * HDIM + cc] = acc[ni][j];
    }
}

// ---------------------------------------------------------------------------
// Kernel 3: local-window attention, LDS-free (q/k/v are L2-resident, 12 MB).
// Thread = (row, quarter p): 16 dims. 17-key window, all loads independent.
// ---------------------------------------------------------------------------
#define DOT4(a, b) ((a).x*(b).x + (a).y*(b).y + (a).z*(b).z + (a).w*(b).w)

__global__ __launch_bounds__(256) void attn_kernel(const float* __restrict__ q,
                                                   const float* __restrict__ k,
                                                   const float* __restrict__ v,
                                                   float* __restrict__ out) {
    int tid = threadIdx.x;
    int b   = blockIdx.y;
    int r0  = blockIdx.x * 64;
    int r   = tid >> 2, p = tid & 3;
    int i_row = r0 + r;

    const float* qb = q + ((long)b * T_SEQ + i_row) * HDIM + p * 16;
    const float* kb = k + (long)b * T_SEQ * HDIM;
    const float* vb = v + (long)b * T_SEQ * HDIM;

    float4 q0 = *(const float4*)(qb + 0);
    float4 q1 = *(const float4*)(qb + 4);
    float4 q2 = *(const float4*)(qb + 8);
    float4 q3 = *(const float4*)(qb + 12);

    float s[17];
    float mx = -1e30f;
    #pragma unroll
    for (int jj = 0; jj < 17; ++jj) {
        int j_row = i_row - 16 + jj;
        float d;
        if (j_row < 0) {
            d = -1e30f;
        } else {
            const float* kr = kb + (long)j_row * HDIM + p * 16;
            float4 k0 = *(const float4*)(kr + 0);
            float4 k1 = *(const float4*)(kr + 4);
            float4 k2 = *(const float4*)(kr + 8);
            float4 k3 = *(const float4*)(kr + 12);
            float pd = DOT4(q0, k0) + DOT4(q1, k1) + DOT4(q2, k2) + DOT4(q3, k3);
            pd += __shfl_xor(pd, 1, 64);     // quad lanes share a row
            pd += __shfl_xor(pd, 2, 64);
            d = pd * 0.125f;                 // / sqrt(64)
        }
        s[jj] = d;
        mx = fmaxf(mx, d);
    }

    float denom = 0.f;
    float4 o0 = {0,0,0,0}, o1 = {0,0,0,0}, o2 = {0,0,0,0}, o3 = {0,0,0,0};
    #pragma unroll
    for (int jj = 0; jj < 17; ++jj) {
        int j_row = i_row - 16 + jj;
        if (j_row < 0) continue;
        float wgt = __expf(s[jj] - mx);
        denom += wgt;
        const float* vr = vb + (long)j_row * HDIM + p * 16;
        float4 v0 = *(const float4*)(vr + 0);
        float4 v1 = *(const float4*)(vr + 4);
        float4 v2 = *(const float4*)(vr + 8);
        float4 v3 = *(const float4*)(vr + 12);
        o0.x += wgt * v0.x; o0.y += wgt * v0.y; o0.z += wgt * v0.z; o0.w += wgt * v0.w;
        o1.x += wgt * v1.x; o1.y += wgt * v1.y; o1.z += wgt * v1.z; o1.w += wgt * v1.w;
        o2.x += wgt * v2.x; o2.y += wgt * v2.y; o2.z += wgt * v2.z; o2.w += wgt * v2.w;
        o3.x += wgt * v3.x; o3.y += wgt * v3.y; o3.z += wgt * v3.z; o3.w += wgt * v3.w;
    }
    float inv = 1.f / denom;
    o0.x *= inv; o0.y *= inv; o0.z *= inv; o0.w *= inv;
    o1.x *= inv; o1.y *= inv; o1.z *= inv; o1.w *= inv;
    o2.x *= inv; o2.y *= inv; o2.z *= inv; o2.w *= inv;
    o3.x *= inv; o3.y *= inv; o3.z *= inv; o3.w *= inv;

    float* ob = out + ((long)b * T_SEQ + i_row) * HDIM + p * 16;
    *(float4*)&ob[0]  = o0;
    *(float4*)&ob[4]  = o1;
    *(float4*)&ob[8]  = o2;
    *(float4*)&ob[12] = o3;
}

// ---------------------------------------------------------------------------
extern "C" void kernel_launch(void* const* d_in, const int* in_sizes, int n_in,
                              void* d_out, int out_size, void* d_ws, size_t ws_size,
                              hipStream_t stream) {
    const float* x  = (const float*)d_in[0];
    const float* Wq = (const float*)d_in[1];
    const float* Wk = (const float*)d_in[2];
    const float* Wv = (const float*)d_in[3];
    float* out = (float*)d_out;

    unsigned short* WT = (unsigned short*)d_ws;                 // 393216 B
    float* qws = (float*)((char*)d_ws + 393216);
    float* kws = qws + (long)NROWS * HDIM;
    float* vws = kws + (long)NROWS * HDIM;

    wt_kernel<<<dim3(768), dim3(256), 0, stream>>>(Wq, Wk, Wv, WT);
    qkv_kernel<<<dim3(NROWS / 64), dim3(256), 0, stream>>>(x, WT, qws, kws, vws);
    attn_kernel<<<dim3(T_SEQ / 64, NB), dim3(256), 0, stream>>>(qws, kws, vws, out);
}

// Round 3
// 171.591 us; speedup vs baseline: 1.1654x; 1.1654x over previous
//
#include <hip/hip_runtime.h>

typedef __bf16 bf16x8 __attribute__((ext_vector_type(8)));
typedef float f32x4 __attribute__((ext_vector_type(4)));

#define T_SEQ 8192
#define NB 2
#define CDIM 1024
#define HDIM 64
#define LPAD 196   // LDS row stride in floats (192 cols + 4 pad) -> 784 B, 16B-aligned

static __device__ __forceinline__ unsigned short f2b(float f) {
    union { float f; unsigned u; } a; a.f = f;
    unsigned r = a.u + 0x7FFFu + ((a.u >> 16) & 1u);   // RNE to bf16
    return (unsigned short)(r >> 16);
}

static __device__ __forceinline__ bf16x8 pack8(float4 a, float4 b) {
    union { bf16x8 v; unsigned short u[8]; } r;
    r.u[0] = f2b(a.x); r.u[1] = f2b(a.y); r.u[2] = f2b(a.z); r.u[3] = f2b(a.w);
    r.u[4] = f2b(b.x); r.u[5] = f2b(b.y); r.u[6] = f2b(b.z); r.u[7] = f2b(b.w);
    return r.v;
}

// ---------------------------------------------------------------------------
// Kernel 1: WT[m][n][k] = W_m[k][n] as bf16 bits.  m in {0=q,1=k,2=v}.
// ---------------------------------------------------------------------------
__global__ __launch_bounds__(256) void wt_kernel(const float* __restrict__ Wq,
                                                 const float* __restrict__ Wk,
                                                 const float* __restrict__ Wv,
                                                 unsigned short* __restrict__ WT) {
    int idx = blockIdx.x * 256 + threadIdx.x;  // < 3*64*1024
    int m   = idx >> 16;
    int rem = idx & 65535;
    int n = rem >> 10, k = rem & 1023;
    const float* W = (m == 0) ? Wq : (m == 1) ? Wk : Wv;
    WT[idx] = f2b(W[k * HDIM + n]);
}

// ---------------------------------------------------------------------------
// Kernel 2: fused QKV projection + windowed attention.
// Block: 960 threads = 15 waves = 5 row-groups x 3 matrices {k,v,q}.
// Each wave: 16 rows x 64 cols MFMA tile, K=1024, B double-buffered in regs
// (issued BEFORE the A prefetch so B-waits never drain A), A 2-deep prefetch.
// q/k/v land in LDS [80][196]; one barrier; 17-key softmax*V from LDS.
// ---------------------------------------------------------------------------
#define DOT4(a, b) ((a).x*(b).x + (a).y*(b).y + (a).z*(b).z + (a).w*(b).w)

__global__ __launch_bounds__(960) void fused_kernel(const float* __restrict__ x,
                                                    const unsigned short* __restrict__ WT,
                                                    float* __restrict__ out) {
    __shared__ float S[80][LPAD];   // cols 0:64 k, 64:128 v, 128:192 q

    int tid  = threadIdx.x;
    int lane = tid & 63;
    int wv   = tid >> 6;            // 0..14
    int rg   = wv / 3;              // row group 0..4
    int cg   = wv % 3;              // 0->k, 1->v, 2->q
    int lr   = lane & 15, lg = lane >> 4;
    int b    = blockIdx.y;
    int r0l  = blockIdx.x * 64;     // local (per-batch) output row base

    // ---- GEMM phase ----
    int rowl = r0l - 16 + rg * 16 + lr;      // local row this lane streams
    if (rowl < 0) rowl = 0;                  // clamped halo (masked in attn)
    const float* xrow = x + ((long)b * T_SEQ + rowl) * CDIM + lg * 8;
    int mm = (cg == 2) ? 0 : (cg + 1);       // matrix index in WT
    const unsigned short* bb = WT + mm * (HDIM * CDIM) + lr * CDIM + lg * 8;

    f32x4 acc[4];
    #pragma unroll
    for (int ni = 0; ni < 4; ++ni) acc[ni] = (f32x4){0.f, 0.f, 0.f, 0.f};

    float4 a0[2], a1[2];
    bf16x8 bfr[2][4];
    a0[0] = *(const float4*)(xrow + 0);
    a1[0] = *(const float4*)(xrow + 4);
    a0[1] = *(const float4*)(xrow + 32);
    a1[1] = *(const float4*)(xrow + 36);
    #pragma unroll
    for (int ni = 0; ni < 4; ++ni)
        bfr[0][ni] = *(const bf16x8*)(bb + ni * 16 * CDIM);

    #pragma unroll
    for (int ks = 0; ks < 32; ++ks) {
        const int cur = ks & 1, nxt = cur ^ 1;
        bf16x8 af = pack8(a0[cur], a1[cur]);
        if (ks < 31) {                        // issue next B (L2) FIRST
            #pragma unroll
            for (int ni = 0; ni < 4; ++ni)
                bfr[nxt][ni] = *(const bf16x8*)(bb + ni * 16 * CDIM + (ks + 1) * 32);
        }
        if (ks < 30) {                        // then A for ks+2 (HBM, 2-deep)
            a0[cur] = *(const float4*)(xrow + (ks + 2) * 32);
            a1[cur] = *(const float4*)(xrow + (ks + 2) * 32 + 4);
        }
        #pragma unroll
        for (int ni = 0; ni < 4; ++ni)
            acc[ni] = __builtin_amdgcn_mfma_f32_16x16x32_bf16(af, bfr[cur][ni], acc[ni], 0, 0, 0);
    }

    // epilogue: C/D layout col=lane&15, row=(lane>>4)*4+j  (~2-way banks: free)
    #pragma unroll
    for (int ni = 0; ni < 4; ++ni)
        #pragma unroll
        for (int j = 0; j < 4; ++j)
            S[rg * 16 + lg * 4 + j][cg * 64 + ni * 16 + lr] = acc[ni][j];

    __syncthreads();

    // ---- attention phase: threads 0..255 (64 rows x 4 dim-quarters) ----
    if (tid < 256) {
        int r = tid >> 2, p = tid & 3;
        int il = r0l + r;                     // local row in [0, 8192)

        const float* qp = &S[r + 16][128 + p * 16];
        float4 q0 = *(const float4*)(qp + 0);
        float4 q1 = *(const float4*)(qp + 4);
        float4 q2 = *(const float4*)(qp + 8);
        float4 q3 = *(const float4*)(qp + 12);

        float s[17];
        float mx = -1e30f;
        #pragma unroll
        for (int jj = 0; jj < 17; ++jj) {
            float d;
            if (il - 16 + jj < 0) {
                d = -1e30f;
            } else {
                const float* kr = &S[r + jj][p * 16];
                float4 k0 = *(const float4*)(kr + 0);
                float4 k1 = *(const float4*)(kr + 4);
                float4 k2 = *(const float4*)(kr + 8);
                float4 k3 = *(const float4*)(kr + 12);
                float pd = DOT4(q0, k0) + DOT4(q1, k1) + DOT4(q2, k2) + DOT4(q3, k3);
                pd += __shfl_xor(pd, 1, 64);   // quad lanes share a row
                pd += __shfl_xor(pd, 2, 64);
                d = pd * 0.125f;               // / sqrt(64)
            }
            s[jj] = d;
            mx = fmaxf(mx, d);
        }

        float denom = 0.f;
        float4 o0 = {0,0,0,0}, o1 = {0,0,0,0}, o2 = {0,0,0,0}, o3 = {0,0,0,0};
        #pragma unroll
        for (int jj = 0; jj < 17; ++jj) {
            if (il - 16 + jj < 0) continue;
            float wgt = __expf(s[jj] - mx);
            denom += wgt;
            const float* vr = &S[r + jj][64 + p * 16];
            float4 v0 = *(const float4*)(vr + 0);
            float4 v1 = *(const float4*)(vr + 4);
            float4 v2 = *(const float4*)(vr + 8);
            float4 v3 = *(const float4*)(vr + 12);
            o0.x += wgt * v0.x; o0.y += wgt * v0.y; o0.z += wgt * v0.z; o0.w += wgt * v0.w;
            o1.x += wgt * v1.x; o1.y += wgt * v1.y; o1.z += wgt * v1.z; o1.w += wgt * v1.w;
            o2.x += wgt * v2.x; o2.y += wgt * v2.y; o2.z += wgt * v2.z; o2.w += wgt * v2.w;
            o3.x += wgt * v3.x; o3.y += wgt * v3.y; o3.z += wgt * v3.z; o3.w += wgt * v3.w;
        }
        float inv = 1.f / denom;
        o0.x *= inv; o0.y *= inv; o0.z *= inv; o0.w *= inv;
        o1.x *= inv; o1.y *= inv; o1.z *= inv; o1.w *= inv;
        o2.x *= inv; o2.y *= inv; o2.z *= inv; o2.w *= inv;
        o3.x *= inv; o3.y *= inv; o3.z *= inv; o3.w *= inv;

        float* ob = out + ((long)b * T_SEQ + il) * HDIM + p * 16;
        *(float4*)&ob[0]  = o0;
        *(float4*)&ob[4]  = o1;
        *(float4*)&ob[8]  = o2;
        *(float4*)&ob[12] = o3;
    }
}

// ---------------------------------------------------------------------------
extern "C" void kernel_launch(void* const* d_in, const int* in_sizes, int n_in,
                              void* d_out, int out_size, void* d_ws, size_t ws_size,
                              hipStream_t stream) {
    const float* x  = (const float*)d_in[0];
    const float* Wq = (const float*)d_in[1];
    const float* Wk = (const float*)d_in[2];
    const float* Wv = (const float*)d_in[3];
    float* out = (float*)d_out;

    unsigned short* WT = (unsigned short*)d_ws;   // 3*64*1024*2 = 393216 B

    wt_kernel<<<dim3(768), dim3(256), 0, stream>>>(Wq, Wk, Wv, WT);
    fused_kernel<<<dim3(T_SEQ / 64, NB), dim3(960), 0, stream>>>(x, WT, out);
}

// Round 4
// 140.951 us; speedup vs baseline: 1.4187x; 1.2174x over previous
//
#include <hip/hip_runtime.h>

typedef __bf16 bf16x8 __attribute__((ext_vector_type(8)));
typedef float f32x4 __attribute__((ext_vector_type(4)));
typedef unsigned int u32x4 __attribute__((ext_vector_type(4)));

#define T_SEQ 8192
#define NB 2
#define CDIM 1024
#define HDIM 64
#define NROWS (NB * T_SEQ)  // 16384
#define LDSW 72             // LDS row stride in ushorts (64 + 8 pad) = 144 B

static __device__ __forceinline__ unsigned bpack(float lo, float hi) {
    unsigned a = __float_as_uint(lo), b = __float_as_uint(hi);
    a = (a + 0x7FFFu + ((a >> 16) & 1u)) >> 16;   // RNE f32->bf16
    b = (b + 0x7FFFu + ((b >> 16) & 1u)) >> 16;
    return a | (b << 16);
}

static __device__ __forceinline__ unsigned short f2b(float f) {
    unsigned u = __float_as_uint(f);
    return (unsigned short)((u + 0x7FFFu + ((u >> 16) & 1u)) >> 16);
}

// ---------------------------------------------------------------------------
// Kernel 1: WT[m][n][k] = W_m[k][n] as bf16 bits.  m in {0=q,1=k,2=v}.
// ---------------------------------------------------------------------------
__global__ __launch_bounds__(256) void wt_kernel(const float* __restrict__ Wq,
                                                 const float* __restrict__ Wk,
                                                 const float* __restrict__ Wv,
                                                 unsigned short* __restrict__ WT) {
    int idx = blockIdx.x * 256 + threadIdx.x;  // < 3*64*1024
    int m   = idx >> 16;
    int rem = idx & 65535;
    int n = rem >> 10, k = rem & 1023;
    const float* W = (m == 0) ? Wq : (m == 1) ? Wk : Wv;
    WT[idx] = f2b(W[k * HDIM + n]);
}

// ---------------------------------------------------------------------------
// Kernel 2: QKV projection.  BM=32, BK=64, 512 blocks (2/CU), 256 thr/4 waves.
// Reg-staged pipeline: B loads first, then x-prefetch (t+1), compute from LDS
// (bf16, padded stride), convert+ds_write, ONE barrier per BK-step.
// Wave w owns cols [w*48, w*48+48) of the 192-wide (q|k|v) output.
// ---------------------------------------------------------------------------
__global__ __launch_bounds__(256, 2) void qkv_kernel(const float* __restrict__ x,
                                                     const unsigned short* __restrict__ WT,
                                                     float* __restrict__ q,
                                                     float* __restrict__ k,
                                                     float* __restrict__ v) {
    __shared__ unsigned short As[2][32 * LDSW];

    int tid  = threadIdx.x;
    int lane = tid & 63;
    int w    = tid >> 6;
    int lr   = lane & 15, lg = lane >> 4;
    long row0 = (long)blockIdx.x * 32;

    // staging role: thread t stages 8 consecutive k-floats of row t/8
    int srow = tid >> 3, sc = tid & 7;
    const float* gsrc = x + (row0 + srow) * CDIM + sc * 8;
    int ldst = srow * LDSW + sc * 8;      // ushort index, 16B-aligned

    // B fragments: WT viewed as [192][1024]; n = w*48 + ni*16 + lr
    const unsigned short* bb = WT + ((long)(w * 48 + lr)) * CDIM + lg * 8;

    f32x4 acc[2][3];
    #pragma unroll
    for (int mi = 0; mi < 2; ++mi)
        #pragma unroll
        for (int ni = 0; ni < 3; ++ni)
            acc[mi][ni] = (f32x4){0.f, 0.f, 0.f, 0.f};

    // ---- prologue: stage BK-step 0 ----
    {
        float4 p0 = *(const float4*)(gsrc + 0);
        float4 p1 = *(const float4*)(gsrc + 4);
        u32x4 pk;
        pk.x = bpack(p0.x, p0.y); pk.y = bpack(p0.z, p0.w);
        pk.z = bpack(p1.x, p1.y); pk.w = bpack(p1.z, p1.w);
        *(u32x4*)&As[0][ldst] = pk;
    }
    __syncthreads();

    for (int t = 0; t < 16; ++t) {
        const int cur = t & 1;

        // ---- B loads for this BK-step (issued FIRST: their wait won't drain staging) ----
        const unsigned short* bt = bb + t * 64;
        u32x4 b00 = *(const u32x4*)(bt);
        u32x4 b01 = *(const u32x4*)(bt + 16 * CDIM);
        u32x4 b02 = *(const u32x4*)(bt + 32 * CDIM);
        u32x4 b10 = *(const u32x4*)(bt + 32);
        u32x4 b11 = *(const u32x4*)(bt + 16 * CDIM + 32);
        u32x4 b12 = *(const u32x4*)(bt + 32 * CDIM + 32);

        // ---- issue x prefetch for step t+1 (consumed after compute) ----
        float4 n0, n1;
        if (t < 15) {
            n0 = *(const float4*)(gsrc + (t + 1) * 64);
            n1 = *(const float4*)(gsrc + (t + 1) * 64 + 4);
        }

        // ---- compute from LDS buf[cur]: 2 k-slices x 2 rowfrags x 3 nfrags ----
        const unsigned short* Ab = As[cur];
        #pragma unroll
        for (int ks = 0; ks < 2; ++ks) {
            u32x4 a0u = *(const u32x4*)&Ab[(0  + lr) * LDSW + ks * 32 + lg * 8];
            u32x4 a1u = *(const u32x4*)&Ab[(16 + lr) * LDSW + ks * 32 + lg * 8];
            bf16x8 a0 = __builtin_bit_cast(bf16x8, a0u);
            bf16x8 a1 = __builtin_bit_cast(bf16x8, a1u);
            bf16x8 f0 = __builtin_bit_cast(bf16x8, ks == 0 ? b00 : b10);
            bf16x8 f1 = __builtin_bit_cast(bf16x8, ks == 0 ? b01 : b11);
            bf16x8 f2 = __builtin_bit_cast(bf16x8, ks == 0 ? b02 : b12);
            acc[0][0] = __builtin_amdgcn_mfma_f32_16x16x32_bf16(a0, f0, acc[0][0], 0, 0, 0);
            acc[1][0] = __builtin_amdgcn_mfma_f32_16x16x32_bf16(a1, f0, acc[1][0], 0, 0, 0);
            acc[0][1] = __builtin_amdgcn_mfma_f32_16x16x32_bf16(a0, f1, acc[0][1], 0, 0, 0);
            acc[1][1] = __builtin_amdgcn_mfma_f32_16x16x32_bf16(a1, f1, acc[1][1], 0, 0, 0);
            acc[0][2] = __builtin_amdgcn_mfma_f32_16x16x32_bf16(a0, f2, acc[0][2], 0, 0, 0);
            acc[1][2] = __builtin_amdgcn_mfma_f32_16x16x32_bf16(a1, f2, acc[1][2], 0, 0, 0);
        }

        // ---- convert + write next buffer, one barrier per step ----
        if (t < 15) {
            u32x4 pk;
            pk.x = bpack(n0.x, n0.y); pk.y = bpack(n0.z, n0.w);
            pk.z = bpack(n1.x, n1.y); pk.w = bpack(n1.z, n1.w);
            *(u32x4*)&As[cur ^ 1][ldst] = pk;
            __syncthreads();
        }
    }

    // ---- epilogue: C/D layout col=lane&15, row=(lane>>4)*4+j ----
    #pragma unroll
    for (int mi = 0; mi < 2; ++mi)
        #pragma unroll
        for (int ni = 0; ni < 3; ++ni) {
            int g   = w * 48 + ni * 16 + lr;   // 0..191
            int mat = g >> 6, cc = g & 63;
            float* op = (mat == 0) ? q : (mat == 1) ? k : v;
            long rbase = row0 + mi * 16 + lg * 4;
            #pragma unroll
            for (int j = 0; j < 4; ++j)
                op[(rbase + j) * HDIM + cc] = acc[mi][ni][j];
        }
}

// ---------------------------------------------------------------------------
// Kernel 3: local-window attention.  Thread = (row, octet p: 8 dims).
// 256 thr = 32 rows/block; grid (256, 2) -> 8 waves/CU.  XCD-chunked swizzle.
// ---------------------------------------------------------------------------
#define DOT4(a, b) ((a).x*(b).x + (a).y*(b).y + (a).z*(b).z + (a).w*(b).w)

__global__ __launch_bounds__(256) void attn_kernel(const float* __restrict__ q,
                                                   const float* __restrict__ k,
                                                   const float* __restrict__ v,
                                                   float* __restrict__ out) {
    int bx   = blockIdx.x;                       // 0..255
    int bswz = (bx & 7) * 32 + (bx >> 3);        // 256 = 8 XCDs x 32: contiguous chunks
    int tid  = threadIdx.x;
    int b    = blockIdx.y;
    int r    = tid >> 3, p = tid & 7;
    int il   = bswz * 32 + r;                    // row within batch

    const float* qp = q + ((long)b * T_SEQ + il) * HDIM + p * 8;
    const float* kb = k + (long)b * T_SEQ * HDIM;
    const float* vb = v + (long)b * T_SEQ * HDIM;

    float4 q0 = *(const float4*)(qp + 0);
    float4 q1 = *(const float4*)(qp + 4);

    float s[17];
    float mx = -1e30f;
    #pragma unroll
    for (int jj = 0; jj < 17; ++jj) {
        int jr = il - 16 + jj;
        float d;
        if (jr < 0) {
            d = -1e30f;
        } else {
            const float* kr = kb + (long)jr * HDIM + p * 8;
            float4 k0 = *(const float4*)(kr + 0);
            float4 k1 = *(const float4*)(kr + 4);
            float pd = DOT4(q0, k0) + DOT4(q1, k1);
            pd += __shfl_xor(pd, 1, 64);          // 8 lanes share a row
            pd += __shfl_xor(pd, 2, 64);
            pd += __shfl_xor(pd, 4, 64);
            d = pd * 0.125f;                      // / sqrt(64)
        }
        s[jj] = d;
        mx = fmaxf(mx, d);
    }

    float denom = 0.f;
    float4 o0 = {0,0,0,0}, o1 = {0,0,0,0};
    #pragma unroll
    for (int jj = 0; jj < 17; ++jj) {
        int jr = il - 16 + jj;
        if (jr < 0) continue;
        float wgt = __expf(s[jj] - mx);
        denom += wgt;
        const float* vr = vb + (long)jr * HDIM + p * 8;
        float4 v0 = *(const float4*)(vr + 0);
        float4 v1 = *(const float4*)(vr + 4);
        o0.x += wgt * v0.x; o0.y += wgt * v0.y; o0.z += wgt * v0.z; o0.w += wgt * v0.w;
        o1.x += wgt * v1.x; o1.y += wgt * v1.y; o1.z += wgt * v1.z; o1.w += wgt * v1.w;
    }
    float inv = 1.f / denom;
    o0.x *= inv; o0.y *= inv; o0.z *= inv; o0.w *= inv;
    o1.x *= inv; o1.y *= inv; o1.z *= inv; o1.w *= inv;

    float* ob = out + ((long)b * T_SEQ + il) * HDIM + p * 8;
    *(float4*)&ob[0] = o0;
    *(float4*)&ob[4] = o1;
}

// ---------------------------------------------------------------------------
extern "C" void kernel_launch(void* const* d_in, const int* in_sizes, int n_in,
                              void* d_out, int out_size, void* d_ws, size_t ws_size,
                              hipStream_t stream) {
    const float* x  = (const float*)d_in[0];
    const float* Wq = (const float*)d_in[1];
    const float* Wk = (const float*)d_in[2];
    const float* Wv = (const float*)d_in[3];
    float* out = (float*)d_out;

    unsigned short* WT = (unsigned short*)d_ws;   // 3*64*1024*2 = 393216 B
    float* qws = (float*)((char*)d_ws + 393216);
    float* kws = qws + (long)NROWS * HDIM;
    float* vws = kws + (long)NROWS * HDIM;

    wt_kernel<<<dim3(768), dim3(256), 0, stream>>>(Wq, Wk, Wv, WT);
    qkv_kernel<<<dim3(NROWS / 32), dim3(256), 0, stream>>>(x, WT, qws, kws, vws);
    attn_kernel<<<dim3(T_SEQ / 32, NB), dim3(256), 0, stream>>>(qws, kws, vws, out);
}

// Round 7
// 129.102 us; speedup vs baseline: 1.5489x; 1.0918x over previous
//
#include <hip/hip_runtime.h>

typedef __bf16 bf16x8 __attribute__((ext_vector_type(8)));
typedef float f32x4 __attribute__((ext_vector_type(4)));
typedef unsigned int u32x4 __attribute__((ext_vector_type(4)));

#define T_SEQ 8192
#define NB 2
#define CDIM 1024
#define HDIM 64
#define NROWS (NB * T_SEQ)  // 16384

static __device__ __forceinline__ unsigned short f2b(float f) {
    unsigned u = __float_as_uint(f);
    return (unsigned short)((u + 0x7FFFu + ((u >> 16) & 1u)) >> 16);
}

static __device__ __forceinline__ unsigned bpack(float lo, float hi) {
    unsigned a = __float_as_uint(lo), b = __float_as_uint(hi);
    a = (a + 0x7FFFu + ((a >> 16) & 1u)) >> 16;   // RNE f32->bf16
    b = (b + 0x7FFFu + ((b >> 16) & 1u)) >> 16;
    return a | (b << 16);
}

// async 16B global->LDS.  LDS dest must be wave-uniform (lane*16 auto-added).
static __device__ __forceinline__ void gll16(const void* g, void* l) {
    __builtin_amdgcn_global_load_lds(
        (const __attribute__((address_space(1))) unsigned int*)(unsigned long long)g,
        (__attribute__((address_space(3))) unsigned int*)(unsigned long long)l,
        16, 0, 0);
}

// ---------------------------------------------------------------------------
// Kernel 1: WT[m][n][k] = W_m[k][n] as bf16 bits.  m in {0=q,1=k,2=v}.
// ---------------------------------------------------------------------------
__global__ __launch_bounds__(256) void wt_kernel(const float* __restrict__ Wq,
                                                 const float* __restrict__ Wk,
                                                 const float* __restrict__ Wv,
                                                 unsigned short* __restrict__ WT) {
    int idx = blockIdx.x * 256 + threadIdx.x;  // < 3*64*1024
    int m   = idx >> 16;
    int rem = idx & 65535;
    int n = rem >> 10, k = rem & 1023;
    const float* W = (m == 0) ? Wq : (m == 1) ? Wk : Wv;
    WT[idx] = f2b(W[k * HDIM + n]);
}

// ---------------------------------------------------------------------------
// Kernel 2: QKV projection, m97 structure.  BM=32, BN=192, BK=64, 16 K-steps.
// global_load_lds for A (f32 x, converted at read) and B (bf16 WT), double
// buffered, ONE barrier/step.  Chunk-XOR swizzle (rule #21): linear LDS dest,
// inverse-swizzled global source, swizzled ds_read -> ~2-way banks.
// 512 blocks x 4 waves, 64 KB LDS -> 2 blocks/CU, 8 waves/CU.
// ---------------------------------------------------------------------------
__global__ __launch_bounds__(256) void qkv_kernel(const float* __restrict__ x,
                                                  const unsigned short* __restrict__ WT,
                                                  float* __restrict__ q,
                                                  float* __restrict__ k,
                                                  float* __restrict__ v) {
    __shared__ float          Af[2][32 * 64];    // 8 KB each:  row = 64 f32 = 8 chunks of 32B
    __shared__ unsigned short Bf[2][192 * 64];   // 24 KB each: row = 64 bf16 = 8 chunks of 16B

    const int tid  = threadIdx.x;
    const int lane = tid & 63;
    const int w    = tid >> 6;
    const int lr   = lane & 15, lg = lane >> 4;
    const long row0 = (long)blockIdx.x * 32;

    // ---- staging source precompute (inverse swizzle on the GLOBAL side) ----
    // A: thread covers LDS bytes L = tid*16 + i*4096 (i=0,1) of the 8 KB buffer.
    //    L -> row r=L>>8, chunk-pos cp=(L>>5)&7, half=(L>>4)&1;
    //    source chunk j = cp ^ (r&7); float offset = j*8 + half*4 (+kt).
    const int aL0 = tid * 16, aL1 = aL0 + 4096;
    const int ar0 = aL0 >> 8, ar1 = aL1 >> 8;
    const int ahalf = (aL0 >> 4) & 1;
    const int aoff0 = ((((aL0 >> 5) & 7) ^ (ar0 & 7)) << 3) + ahalf * 4;
    const int aoff1 = ((((aL1 >> 5) & 7) ^ (ar1 & 7)) << 3) + ahalf * 4;
    const float* asrc0 = x + (row0 + ar0) * CDIM + aoff0;
    const float* asrc1 = x + (row0 + ar1) * CDIM + aoff1;

    // B: L = tid*16 + i*4096 (i=0..5) of the 24 KB buffer.
    //    r=L>>7, cp=(L>>4)&7; source chunk j = cp ^ (r&7); ushort off = j*8 (+kt).
    const unsigned short* bsrc[6];
    #pragma unroll
    for (int i = 0; i < 6; ++i) {
        int L = tid * 16 + i * 4096;
        int r = L >> 7;
        int j = ((L >> 4) & 7) ^ (r & 7);
        bsrc[i] = WT + r * CDIM + j * 8;
    }
    const int wlds = w << 10;   // wave-uniform LDS byte base offset

    f32x4 acc[2][3];
    #pragma unroll
    for (int mi = 0; mi < 2; ++mi)
        #pragma unroll
        for (int ni = 0; ni < 3; ++ni)
            acc[mi][ni] = (f32x4){0.f, 0.f, 0.f, 0.f};

    #define STAGE(buf, kt)                                                        \
        do {                                                                      \
            gll16(asrc0 + (kt), (char*)&Af[buf][0] + wlds);                       \
            gll16(asrc1 + (kt), (char*)&Af[buf][0] + wlds + 4096);                \
            _Pragma("unroll")                                                     \
            for (int i = 0; i < 6; ++i)                                           \
                gll16(bsrc[i] + (kt), (char*)&Bf[buf][0] + wlds + i * 4096);      \
        } while (0)

    STAGE(0, 0);
    __syncthreads();   // compiler drains vmcnt(0) before s_barrier

    // read-side swizzled positions (constant per thread)
    const int amsk = lr & 7;
    for (int t = 0; t < 16; ++t) {
        const int cur = t & 1;
        if (t < 15) STAGE(cur ^ 1, (t + 1) * 64);

        const float*          Ab = Af[cur];
        const unsigned short* Bb = Bf[cur];
        #pragma unroll
        for (int ks = 0; ks < 2; ++ks) {
            const int apos = (((ks << 2) + lg) ^ amsk) << 3;   // float offset in row
            f32x4 l0 = *(const f32x4*)&Ab[lr * 64 + apos];
            f32x4 h0 = *(const f32x4*)&Ab[lr * 64 + apos + 4];
            f32x4 l1 = *(const f32x4*)&Ab[(16 + lr) * 64 + apos];
            f32x4 h1 = *(const f32x4*)&Ab[(16 + lr) * 64 + apos + 4];
            u32x4 p0, p1;
            p0.x = bpack(l0[0], l0[1]); p0.y = bpack(l0[2], l0[3]);
            p0.z = bpack(h0[0], h0[1]); p0.w = bpack(h0[2], h0[3]);
            p1.x = bpack(l1[0], l1[1]); p1.y = bpack(l1[2], l1[3]);
            p1.z = bpack(h1[0], h1[1]); p1.w = bpack(h1[2], h1[3]);
            bf16x8 a0 = __builtin_bit_cast(bf16x8, p0);
            bf16x8 a1 = __builtin_bit_cast(bf16x8, p1);
            #pragma unroll
            for (int ni = 0; ni < 3; ++ni) {
                int brow = w * 48 + ni * 16 + lr;
                int bpos = (((ks << 2) + lg) ^ (brow & 7)) << 3;  // ushort offset
                u32x4 bu = *(const u32x4*)&Bb[brow * 64 + bpos];
                bf16x8 bfv = __builtin_bit_cast(bf16x8, bu);
                acc[0][ni] = __builtin_amdgcn_mfma_f32_16x16x32_bf16(a0, bfv, acc[0][ni], 0, 0, 0);
                acc[1][ni] = __builtin_amdgcn_mfma_f32_16x16x32_bf16(a1, bfv, acc[1][ni], 0, 0, 0);
            }
        }
        __syncthreads();
    }
    #undef STAGE

    // ---- epilogue: C/D layout col=lane&15, row=(lane>>4)*4+j ----
    #pragma unroll
    for (int mi = 0; mi < 2; ++mi)
        #pragma unroll
        for (int ni = 0; ni < 3; ++ni) {
            int g   = w * 48 + ni * 16 + lr;   // 0..191
            int mat = g >> 6, cc = g & 63;
            float* op = (mat == 0) ? q : (mat == 1) ? k : v;
            long rbase = row0 + mi * 16 + lg * 4;
            #pragma unroll
            for (int j = 0; j < 4; ++j)
                op[(rbase + j) * HDIM + cc] = acc[mi][ni][j];
        }
}

// ---------------------------------------------------------------------------
// Kernel 3: local-window attention.  Thread = (row, octet p: 8 dims).
// 256 thr = 32 rows/block; grid (256, 2).  NO swizzle: linear block id keeps
// each attn block on the same XCD whose L2 holds its q/k/v (written by the
// same-index qkv block).
// ---------------------------------------------------------------------------
#define DOT4(a, b) ((a).x*(b).x + (a).y*(b).y + (a).z*(b).z + (a).w*(b).w)

__global__ __launch_bounds__(256) void attn_kernel(const float* __restrict__ q,
                                                   const float* __restrict__ k,
                                                   const float* __restrict__ v,
                                                   float* __restrict__ out) {
    int tid = threadIdx.x;
    int b   = blockIdx.y;
    int r   = tid >> 3, p = tid & 7;
    int il  = blockIdx.x * 32 + r;               // row within batch

    const float* qp = q + ((long)b * T_SEQ + il) * HDIM + p * 8;
    const float* kb = k + (long)b * T_SEQ * HDIM;
    const float* vb = v + (long)b * T_SEQ * HDIM;

    float4 q0 = *(const float4*)(qp + 0);
    float4 q1 = *(const float4*)(qp + 4);

    float s[17];
    float mx = -1e30f;
    #pragma unroll
    for (int jj = 0; jj < 17; ++jj) {
        int jr = il - 16 + jj;
        float d;
        if (jr < 0) {
            d = -1e30f;
        } else {
            const float* kr = kb + (long)jr * HDIM + p * 8;
            float4 k0 = *(const float4*)(kr + 0);
            float4 k1 = *(const float4*)(kr + 4);
            float pd = DOT4(q0, k0) + DOT4(q1, k1);
            pd += __shfl_xor(pd, 1, 64);          // 8 lanes share a row
            pd += __shfl_xor(pd, 2, 64);
            pd += __shfl_xor(pd, 4, 64);
            d = pd * 0.125f;                      // / sqrt(64)
        }
        s[jj] = d;
        mx = fmaxf(mx, d);
    }

    float denom = 0.f;
    float4 o0 = {0,0,0,0}, o1 = {0,0,0,0};
    #pragma unroll
    for (int jj = 0; jj < 17; ++jj) {
        int jr = il - 16 + jj;
        if (jr < 0) continue;
        float wgt = __expf(s[jj] - mx);
        denom += wgt;
        const float* vr = vb + (long)jr * HDIM + p * 8;
        float4 v0 = *(const float4*)(vr + 0);
        float4 v1 = *(const float4*)(vr + 4);
        o0.x += wgt * v0.x; o0.y += wgt * v0.y; o0.z += wgt * v0.z; o0.w += wgt * v0.w;
        o1.x += wgt * v1.x; o1.y += wgt * v1.y; o1.z += wgt * v1.z; o1.w += wgt * v1.w;
    }
    float inv = 1.f / denom;
    o0.x *= inv; o0.y *= inv; o0.z *= inv; o0.w *= inv;
    o1.x *= inv; o1.y *= inv; o1.z *= inv; o1.w *= inv;

    float* ob = out + ((long)b * T_SEQ + il) * HDIM + p * 8;
    *(float4*)&ob[0] = o0;
    *(float4*)&ob[4] = o1;
}

// ---------------------------------------------------------------------------
extern "C" void kernel_launch(void* const* d_in, const int* in_sizes, int n_in,
                              void* d_out, int out_size, void* d_ws, size_t ws_size,
                              hipStream_t stream) {
    const float* x  = (const float*)d_in[0];
    const float* Wq = (const float*)d_in[1];
    const float* Wk = (const float*)d_in[2];
    const float* Wv = (const float*)d_in[3];
    float* out = (float*)d_out;

    unsigned short* WT = (unsigned short*)d_ws;   // 3*64*1024*2 = 393216 B
    float* qws = (float*)((char*)d_ws + 393216);
    float* kws = qws + (long)NROWS * HDIM;
    float* vws = kws + (long)NROWS * HDIM;

    wt_kernel<<<dim3(768), dim3(256), 0, stream>>>(Wq, Wk, Wv, WT);
    qkv_kernel<<<dim3(NROWS / 32), dim3(256), 0, stream>>>(x, WT, qws, kws, vws);
    attn_kernel<<<dim3(T_SEQ / 32, NB), dim3(256), 0, stream>>>(qws, kws, vws, out);
}